// Round 1
// baseline (378.761 us; speedup 1.0000x reference)
//
#include <hip/hip_runtime.h>

#define B 64
#define H 56
#define W 56
#define C 256
#define ROUTES 4
#define CONV_OUT 64
#define BN_EPS 0.001f
#define RW (C / ROUTES)          // 64 channels per route

#define NSLOT 9                   // 0 S_ee, 1 S_eo, 2 S_oe, 3 S_oo, 4 c0e, 5 c0o, 6 r0e, 7 r0o, 8 x00
#define ACC_FLOATS (B * NSLOT * C)
#define X_SIZE ((long)B * H * W * RW)

#define ROWS_PER_BLK 4
#define CHUNKS (H / ROWS_PER_BLK)  // 14

__device__ __forceinline__ void f4add(float4& a, const float4& v) {
    a.x += v.x; a.y += v.y; a.z += v.z; a.w += v.w;
}

// ---------------------------------------------------------------------------
// Kernel 1: parity-quadrant reduction over raw inputs.
// Block = (b, 4-row chunk). Thread t: cg = t&63 -> channels [4cg..4cg+3] as
// float4; wg = t>>6 in 0..3 -> handles w = wg, wg+4, ... (fixed w-parity).
// Wave = fixed wg, lanes sweep cg -> each load is 64*16B = 1KB contiguous.
// ---------------------------------------------------------------------------
__global__ __launch_bounds__(256) void k_reduce(const float* __restrict__ x,
                                                float* __restrict__ acc) {
    int blk = blockIdx.x;           // 0 .. B*CHUNKS-1
    int b = blk / CHUNKS;
    int h0 = (blk % CHUNKS) * ROWS_PER_BLK;
    int tid = threadIdx.x;
    int cg = tid & 63;
    int wg = tid >> 6;              // 0..3
    int wp = wg & 1;                // w parity

    const float4* xv = (const float4*)x;

    float4 s0 = {0,0,0,0};          // h even quadrant (this thread's w-parity)
    float4 s1 = {0,0,0,0};          // h odd quadrant
    float4 c0e = {0,0,0,0};         // col-0, h even (wg==0 only)
    float4 c0o = {0,0,0,0};         // col-0, h odd  (wg==0 only)
    float4 r0  = {0,0,0,0};         // row-0, this w-parity (chunk 0 only)
    float4 x00 = {0,0,0,0};

    for (int hh = 0; hh < ROWS_PER_BLK; ++hh) {
        int h = h0 + hh;
        long base = ((long)(b * H + h) * W) * (C / 4) + cg;   // float4 units
        float4 rs = {0,0,0,0};
        for (int w = wg; w < W; w += 4) {
            float4 v = xv[base + (long)w * (C / 4)];
            f4add(rs, v);
            if (wg == 0 && w == 0) {
                if ((h & 1) == 0) f4add(c0e, v); else f4add(c0o, v);
                if (h == 0) x00 = v;
            }
        }
        if (h & 1) f4add(s1, rs); else f4add(s0, rs);
        if (h == 0) r0 = rs;
    }

    float* accb = acc + (long)b * NSLOT * C;
    int c = cg * 4;
    #define AT4(slot, v) { float* p = accb + (slot) * C + c; \
        atomicAdd(p+0, (v).x); atomicAdd(p+1, (v).y); \
        atomicAdd(p+2, (v).z); atomicAdd(p+3, (v).w); }

    AT4(0 + wp, s0);                // h even -> S_ee / S_eo
    AT4(2 + wp, s1);                // h odd  -> S_oe / S_oo
    if (wg == 0) { AT4(4, c0e); AT4(5, c0o); }
    if (h0 == 0) {
        AT4(6 + wp, r0);            // row-0 sums (wg 0&2 -> slot6, 1&3 -> slot7)
        if (wg == 0) {              // unique writer per (b,c): plain store
            float* p = accb + 8 * C + c;
            p[0] = x00.x; p[1] = x00.y; p[2] = x00.z; p[3] = x00.w;
        }
    }
    #undef AT4
}

// ---------------------------------------------------------------------------
// Kernel 2: per-batch routing. Reconstruct the 9 grid sums, apply BN affine,
// contract with conv weights (folded conv+mean), FC, argmax.
// ---------------------------------------------------------------------------
__global__ __launch_bounds__(256) void k_route(const float* __restrict__ acc,
                                               const float* __restrict__ gamma,
                                               const float* __restrict__ beta,
                                               const float* __restrict__ mmean,
                                               const float* __restrict__ mvar,
                                               const float* __restrict__ conv_w,
                                               const float* __restrict__ conv_b,
                                               const float* __restrict__ fc_w,
                                               const float* __restrict__ fc_b,
                                               float* __restrict__ out_routing,
                                               int* __restrict__ route) {
    __shared__ float tl[9][C];            // 9 KB: BN-applied grid sums
    __shared__ float part[4][CONV_OUT];
    __shared__ float cm[CONV_OUT];
    __shared__ float rxs[ROUTES];

    int b = blockIdx.x;
    int c = threadIdx.x;
    const float* ab = acc + (long)b * NSLOT * C;

    float See = ab[0*C+c], Seo = ab[1*C+c], Soe = ab[2*C+c], Soo = ab[3*C+c];
    float c0e = ab[4*C+c], c0o = ab[5*C+c];
    float r0e = ab[6*C+c], r0o = ab[7*C+c], x00 = ab[8*C+c];

    float a  = gamma[c] * rsqrtf(mvar[c] + BN_EPS);
    float bb = beta[c] - mmean[c] * a;

    // Sx[kh*3+kw]: grid sums of raw x (ih=2oh+kh, ih=56 padded => kh/kw==2
    // grid = even grid minus row0/col0)
    float Sx[9] = { See,             Seo,             See - c0e,
                    Soe,             Soo,             Soe - c0o,
                    See - r0e,       Seo - r0o,       See - r0e - c0e + x00 };
    const float cnt[9] = { 784.f, 784.f, 756.f,
                           784.f, 784.f, 756.f,
                           756.f, 756.f, 729.f };   // valid positions per tap
    for (int k = 0; k < 9; ++k) tl[k][c] = a * Sx[k] + bb * cnt[k];
    __syncthreads();

    // thread = g*64 + o : output channel o, input-channel chunk g (64 ch)
    int o = threadIdx.x & 63;
    int g = threadIdx.x >> 6;
    float p = 0.f;
    for (int cc = g * 64; cc < g * 64 + 64; ++cc) {
        #pragma unroll
        for (int k = 0; k < 9; ++k)
            p += tl[k][cc] * conv_w[(k * C + cc) * CONV_OUT + o];  // (3,3,C,O)
    }
    part[g][o] = p;
    __syncthreads();

    if (threadIdx.x < CONV_OUT) {
        int o2 = threadIdx.x;
        float s = part[0][o2] + part[1][o2] + part[2][o2] + part[3][o2];
        cm[o2] = s * (1.f / 784.f) + conv_b[o2];   // mean of conv incl. bias
    }
    __syncthreads();

    if (threadIdx.x < ROUTES) {
        int r = threadIdx.x;
        float s = fc_b[r];
        for (int o2 = 0; o2 < CONV_OUT; ++o2) s += cm[o2] * fc_w[o2 * ROUTES + r];
        rxs[r] = s;
        out_routing[b * ROUTES + r] = s;
    }
    __syncthreads();

    if (threadIdx.x == 0) {
        int best = 0;                       // jnp.argmax: first max wins
        for (int r = 1; r < ROUTES; ++r) if (rxs[r] > rxs[best]) best = r;
        route[b] = best;
    }
}

// ---------------------------------------------------------------------------
// Kernel 3: gather 64 contiguous channels of the raw input per routed batch.
// One float4 per thread; fully coalesced read and write.
// ---------------------------------------------------------------------------
__global__ __launch_bounds__(256) void k_gather(const float* __restrict__ x,
                                                const int* __restrict__ route,
                                                float* __restrict__ out) {
    long idx = (long)blockIdx.x * blockDim.x + threadIdx.x;  // float4 id
    int j = (int)(idx & 15);                                 // 16 float4 / pixel
    long pixel = idx >> 4;
    int b = (int)(pixel / (H * W));
    const float4* xv = (const float4*)x;
    float4 v = xv[pixel * (C / 4) + (long)route[b] * (RW / 4) + j];
    ((float4*)out)[idx] = v;
}

extern "C" void kernel_launch(void* const* d_in, const int* in_sizes, int n_in,
                              void* d_out, int out_size, void* d_ws, size_t ws_size,
                              hipStream_t stream) {
    const float* inputs = (const float*)d_in[0];
    const float* gamma  = (const float*)d_in[1];
    const float* beta   = (const float*)d_in[2];
    const float* mmean  = (const float*)d_in[3];
    const float* mvar   = (const float*)d_in[4];
    const float* conv_w = (const float*)d_in[5];
    const float* conv_b = (const float*)d_in[6];
    const float* fc_w   = (const float*)d_in[7];
    const float* fc_b   = (const float*)d_in[8];

    float* out   = (float*)d_out;
    float* acc   = (float*)d_ws;
    int*   route = (int*)((char*)d_ws + ACC_FLOATS * sizeof(float));

    // ws is re-poisoned to 0xAA before every launch: zero the accumulators.
    hipMemsetAsync(d_ws, 0, ACC_FLOATS * sizeof(float), stream);

    k_reduce<<<B * CHUNKS, 256, 0, stream>>>(inputs, acc);
    k_route<<<B, 256, 0, stream>>>(acc, gamma, beta, mmean, mvar,
                                   conv_w, conv_b, fc_w, fc_b,
                                   out + X_SIZE, route);
    long n4 = X_SIZE / 4;                    // 3,211,264 float4s
    k_gather<<<(int)(n4 / 256), 256, 0, stream>>>(inputs, route, out);
}

// Round 2
// 356.671 us; speedup vs baseline: 1.0619x; 1.0619x over previous
//
#include <hip/hip_runtime.h>

#define B 64
#define H 56
#define W 56
#define C 256
#define ROUTES 4
#define CONV_OUT 64
#define BN_EPS 0.001f
#define RW (C / ROUTES)            // 64 channels per route
#define X_SIZE ((long)B * H * W * RW)

#define PAIRS (H / 2)              // 28 row-pairs (even row 2j, odd row 2j+1)

// ws layout (floats):
//  acc4  [B][PAIRS][8][C]  slot = hpar*4 + wg   (per-block quadrant partials)
//  accc  [B][PAIRS][2][C]  col-0 value of even row / odd row
//  accr  [B][4][C]         row-0 sum per wg (block j==0 only)
//  accx  [B][C]            x[b][0][0][:]
#define S4 ((long)B * PAIRS * 8 * C)
#define SC ((long)B * PAIRS * 2 * C)
#define SR ((long)B * 4 * C)
#define SX ((long)B * C)
#define OFF4 0L
#define OFFC (OFF4 + S4)
#define OFFR (OFFC + SC)
#define OFFX (OFFR + SR)
#define WS_FLOATS (OFFX + SX)

__device__ __forceinline__ void f4add(float4& a, const float4& v) {
    a.x += v.x; a.y += v.y; a.z += v.z; a.w += v.w;
}

// ---------------------------------------------------------------------------
// Kernel 1: parity-quadrant partial sums, atomic-free.
// Block = (b, row-pair j). Thread t: cg = t&63 -> float4 of channels
// [4cg..4cg+4); wg = t>>6 -> w = wg, wg+4, ... (fixed w-parity). Each wave
// load = 64 lanes x 16B = 1KB contiguous. 14 loads per row are issued into
// independent registers (full unroll), then tree-summed -> deep MLP.
// ---------------------------------------------------------------------------
__global__ __launch_bounds__(256) void k_reduce(const float* __restrict__ x,
                                                float* __restrict__ ws) {
    int blk = blockIdx.x;               // b*PAIRS + j
    int b = blk / PAIRS;
    int j = blk % PAIRS;
    int tid = threadIdx.x;
    int cg = tid & 63;
    int wg = tid >> 6;                  // 0..3

    const float4* xv = (const float4*)x;
    long row0 = ((long)(b * H + 2 * j) * W) * (C / 4) + cg;   // float4 units
    long row1 = row0 + (long)W * (C / 4);

    float4 r0[14], r1[14];
    #pragma unroll
    for (int i = 0; i < 14; ++i) r0[i] = xv[row0 + (long)(wg + 4 * i) * (C / 4)];
    #pragma unroll
    for (int i = 0; i < 14; ++i) r1[i] = xv[row1 + (long)(wg + 4 * i) * (C / 4)];

    // tree-sum each row (independent chains)
    float4 s0 = {0,0,0,0}, s1 = {0,0,0,0};
    {
        float4 a = {0,0,0,0}, bq = {0,0,0,0};
        #pragma unroll
        for (int i = 0; i < 14; i += 2) { f4add(a, r0[i]); f4add(bq, r0[i+1]); }
        f4add(s0, a); f4add(s0, bq);
    }
    {
        float4 a = {0,0,0,0}, bq = {0,0,0,0};
        #pragma unroll
        for (int i = 0; i < 14; i += 2) { f4add(a, r1[i]); f4add(bq, r1[i+1]); }
        f4add(s1, a); f4add(s1, bq);
    }

    int c4 = cg;                        // float4 index within C
    float4* acc4 = (float4*)(ws + OFF4) + ((long)blk * 8 + wg) * (C / 4) + c4;
    acc4[0]             = s0;           // slot hpar=0, this wg
    acc4[4 * (C / 4)]   = s1;           // slot hpar=1, this wg

    if (wg == 0) {                      // col-0 values (w==0 is in wg 0, i==0)
        float4* accc = (float4*)(ws + OFFC) + ((long)blk * 2) * (C / 4) + c4;
        accc[0]       = r0[0];          // even row col-0
        accc[C / 4]   = r1[0];          // odd row col-0
    }
    if (j == 0) {                       // row 0 is the even row of pair 0
        float4* accr = (float4*)(ws + OFFR) + ((long)b * 4 + wg) * (C / 4) + c4;
        accr[0] = s0;                   // per-wg row-0 sum
        if (wg == 0) {
            float4* accx = (float4*)(ws + OFFX) + (long)b * (C / 4) + c4;
            accx[0] = r0[0];            // x[b][0][0][:]
        }
    }
}

// ---------------------------------------------------------------------------
// Kernel 2: per-batch routing. Reduce partials -> 9 grid sums, BN affine,
// folded conv+mean contraction, FC, argmax.
// ---------------------------------------------------------------------------
__global__ __launch_bounds__(256) void k_route(const float* __restrict__ ws,
                                               const float* __restrict__ gamma,
                                               const float* __restrict__ beta,
                                               const float* __restrict__ mmean,
                                               const float* __restrict__ mvar,
                                               const float* __restrict__ conv_w,
                                               const float* __restrict__ conv_b,
                                               const float* __restrict__ fc_w,
                                               const float* __restrict__ fc_b,
                                               float* __restrict__ out_routing,
                                               int* __restrict__ route) {
    __shared__ float tl[9][C];            // 9 KB: BN-applied grid sums
    __shared__ float part[4][CONV_OUT];
    __shared__ float cm[CONV_OUT];
    __shared__ float rxs[ROUTES];

    int b = blockIdx.x;
    int c = threadIdx.x;

    float See = 0, Seo = 0, Soe = 0, Soo = 0, c0e = 0, c0o = 0;
    const float* a4 = ws + OFF4 + (long)b * PAIRS * 8 * C;
    for (int j = 0; j < PAIRS; ++j) {
        const float* p = a4 + (long)j * 8 * C + c;
        See += p[0 * C] + p[2 * C];       // hpar0, wg 0&2 (even w)
        Seo += p[1 * C] + p[3 * C];       // hpar0, wg 1&3 (odd w)
        Soe += p[4 * C] + p[6 * C];
        Soo += p[5 * C] + p[7 * C];
    }
    const float* pc = ws + OFFC + (long)b * PAIRS * 2 * C;
    for (int j = 0; j < PAIRS; ++j) {
        c0e += pc[(long)(2 * j) * C + c];
        c0o += pc[(long)(2 * j + 1) * C + c];
    }
    const float* pr = ws + OFFR + (long)b * 4 * C;
    float r0e = pr[0 * C + c] + pr[2 * C + c];
    float r0o = pr[1 * C + c] + pr[3 * C + c];
    float x00 = ws[OFFX + (long)b * C + c];

    float a  = gamma[c] * rsqrtf(mvar[c] + BN_EPS);
    float bb = beta[c] - mmean[c] * a;

    // Sx[kh*3+kw]: grid sums of raw x (ih=2oh+kh; ih/iw==56 are zero-pad =>
    // kh/kw==2 grid = even grid minus row0/col0)
    float Sx[9] = { See,             Seo,             See - c0e,
                    Soe,             Soo,             Soe - c0o,
                    See - r0e,       Seo - r0o,       See - r0e - c0e + x00 };
    const float cnt[9] = { 784.f, 784.f, 756.f,
                           784.f, 784.f, 756.f,
                           756.f, 756.f, 729.f };   // valid positions per tap
    #pragma unroll
    for (int k = 0; k < 9; ++k) tl[k][c] = a * Sx[k] + bb * cnt[k];
    __syncthreads();

    // thread = g*64 + o : output channel o, input-channel chunk g (64 ch)
    int o = threadIdx.x & 63;
    int g = threadIdx.x >> 6;
    float p = 0.f;
    for (int cc = g * 64; cc < g * 64 + 64; ++cc) {
        #pragma unroll
        for (int k = 0; k < 9; ++k)
            p += tl[k][cc] * conv_w[(k * C + cc) * CONV_OUT + o];  // (3,3,C,O)
    }
    part[g][o] = p;
    __syncthreads();

    if (threadIdx.x < CONV_OUT) {
        int o2 = threadIdx.x;
        float s = part[0][o2] + part[1][o2] + part[2][o2] + part[3][o2];
        cm[o2] = s * (1.f / 784.f) + conv_b[o2];   // mean of conv incl. bias
    }
    __syncthreads();

    if (threadIdx.x < ROUTES) {
        int r = threadIdx.x;
        float s = fc_b[r];
        for (int o2 = 0; o2 < CONV_OUT; ++o2) s += cm[o2] * fc_w[o2 * ROUTES + r];
        rxs[r] = s;
        out_routing[b * ROUTES + r] = s;
    }
    __syncthreads();

    if (threadIdx.x == 0) {
        int best = 0;                       // jnp.argmax: first max wins
        for (int r = 1; r < ROUTES; ++r) if (rxs[r] > rxs[best]) best = r;
        route[b] = best;
    }
}

// ---------------------------------------------------------------------------
// Kernel 3: gather 64 contiguous channels of the raw input per routed batch.
// One float4 per thread; fully coalesced read and write.
// ---------------------------------------------------------------------------
__global__ __launch_bounds__(256) void k_gather(const float* __restrict__ x,
                                                const int* __restrict__ route,
                                                float* __restrict__ out) {
    long idx = (long)blockIdx.x * blockDim.x + threadIdx.x;  // float4 id
    int j = (int)(idx & 15);                                 // 16 float4 / pixel
    long pixel = idx >> 4;
    int b = (int)(pixel / (H * W));
    const float4* xv = (const float4*)x;
    float4 v = xv[pixel * (C / 4) + (long)route[b] * (RW / 4) + j];
    ((float4*)out)[idx] = v;
}

extern "C" void kernel_launch(void* const* d_in, const int* in_sizes, int n_in,
                              void* d_out, int out_size, void* d_ws, size_t ws_size,
                              hipStream_t stream) {
    const float* inputs = (const float*)d_in[0];
    const float* gamma  = (const float*)d_in[1];
    const float* beta   = (const float*)d_in[2];
    const float* mmean  = (const float*)d_in[3];
    const float* mvar   = (const float*)d_in[4];
    const float* conv_w = (const float*)d_in[5];
    const float* conv_b = (const float*)d_in[6];
    const float* fc_w   = (const float*)d_in[7];
    const float* fc_b   = (const float*)d_in[8];

    float* out   = (float*)d_out;
    float* ws    = (float*)d_ws;
    int*   route = (int*)((char*)d_ws + WS_FLOATS * sizeof(float));

    // All ws regions consumed downstream are fully written first -> no memset.
    k_reduce<<<B * PAIRS, 256, 0, stream>>>(inputs, ws);
    k_route<<<B, 256, 0, stream>>>(ws, gamma, beta, mmean, mvar,
                                   conv_w, conv_b, fc_w, fc_b,
                                   out + X_SIZE, route);
    long n4 = X_SIZE / 4;                    // 3,211,264 float4s
    k_gather<<<(int)(n4 / 256), 256, 0, stream>>>(inputs, route, out);
}

// Round 4
// 354.011 us; speedup vs baseline: 1.0699x; 1.0075x over previous
//
#include <hip/hip_runtime.h>

#define B 64
#define H 56
#define W 56
#define C 256
#define ROUTES 4
#define CONV_OUT 64
#define BN_EPS 0.001f
#define RW (C / ROUTES)            // 64 channels per route
#define X_SIZE ((long)B * H * W * RW)

// ws layout (floats): per (b,h): [3][C] = {even-w row sum, odd-w row sum, col-0 value}
#define WS_FLOATS ((long)B * H * 3 * C)     // 11 MB

typedef float floatx4 __attribute__((ext_vector_type(4)));  // native vector for nontemporal builtins

__device__ __forceinline__ void f4add(float4& a, const float4& v) {
    a.x += v.x; a.y += v.y; a.z += v.z; a.w += v.w;
}

// ---------------------------------------------------------------------------
// Kernel 1: per-row parity sums. Block = one (b,h) row, 256 threads.
// Thread t: cg = t&63 -> float4 of channels [4cg..4cg+4); wg = t>>6 ->
// w = wg, wg+4, ..., wg+52 (fixed w-parity). Wave load = 64x16B = 1KB
// contiguous; 4 waves at same i cover 4KB contiguous. 14 independent loads
// per thread (56 data VGPRs - no spill risk), tree-summed, then LDS-combined
// across w-groups to 2 parity sums + col-0 -> 11 MB partials total.
// ---------------------------------------------------------------------------
__global__ __launch_bounds__(256) void k_reduce(const float* __restrict__ x,
                                                float* __restrict__ ws) {
    int blk = blockIdx.x;               // b*H + h
    int tid = threadIdx.x;
    int cg = tid & 63;
    int wg = tid >> 6;                  // 0..3

    const float4* xv = (const float4*)x;
    long base = (long)blk * W * (C / 4) + cg;

    float4 v[14];
    #pragma unroll
    for (int i = 0; i < 14; ++i) v[i] = xv[base + (long)(wg + 4 * i) * (C / 4)];

    float4 a = {0,0,0,0}, b4 = {0,0,0,0};
    #pragma unroll
    for (int i = 0; i < 14; i += 2) { f4add(a, v[i]); f4add(b4, v[i + 1]); }
    f4add(a, b4);                       // sum over w === wg (mod 4)

    __shared__ float4 lds[4][64];       // 4 KB
    lds[wg][cg] = a;

    float4* w3 = (float4*)ws + (long)blk * 3 * (C / 4);
    if (wg == 0) w3[2 * (C / 4) + cg] = v[0];      // col-0 value x[b][h][0][:]
    __syncthreads();
    if (wg == 0) {                       // even-w sum (w=0,2,.. = wg 0 & 2)
        float4 e = lds[0][cg]; f4add(e, lds[2][cg]);
        w3[cg] = e;
    } else if (wg == 1) {                // odd-w sum (wg 1 & 3)
        float4 o = lds[1][cg]; f4add(o, lds[3][cg]);
        w3[C / 4 + cg] = o;
    }
}

// ---------------------------------------------------------------------------
// Kernel 2: per-batch routing. Reduce per-row partials -> 9 grid sums,
// BN affine, folded conv+mean contraction, FC, argmax.
// ---------------------------------------------------------------------------
__global__ __launch_bounds__(256) void k_route(const float* __restrict__ ws,
                                               const float* __restrict__ gamma,
                                               const float* __restrict__ beta,
                                               const float* __restrict__ mmean,
                                               const float* __restrict__ mvar,
                                               const float* __restrict__ conv_w,
                                               const float* __restrict__ conv_b,
                                               const float* __restrict__ fc_w,
                                               const float* __restrict__ fc_b,
                                               float* __restrict__ out_routing,
                                               int* __restrict__ route) {
    __shared__ float tl[9][C];            // 9 KB: BN-applied grid sums
    __shared__ float part[4][CONV_OUT];
    __shared__ float cm[CONV_OUT];
    __shared__ float rxs[ROUTES];

    int b = blockIdx.x;
    int c = threadIdx.x;

    const float* base = ws + (long)b * H * 3 * C;
    float See = 0, Seo = 0, Soe = 0, Soo = 0, c0e = 0, c0o = 0;
    for (int h = 0; h < H; h += 2) {
        const float* pe = base + (long)h * 3 * C;        // even row
        const float* po = pe + 3 * C;                    // odd row
        See += pe[c];          Seo += pe[C + c];     c0e += pe[2 * C + c];
        Soe += po[c];          Soo += po[C + c];     c0o += po[2 * C + c];
    }
    float r0e = base[c];                 // row-0 even-w sum
    float r0o = base[C + c];             // row-0 odd-w sum
    float x00 = base[2 * C + c];         // x[b][0][0][c]

    float a  = gamma[c] * rsqrtf(mvar[c] + BN_EPS);
    float bb = beta[c] - mmean[c] * a;

    // Sx[kh*3+kw]: grid sums of raw x (ih=2oh+kh; ih/iw==56 are zero-pad =>
    // kh/kw==2 grid = even grid minus row0/col0)
    float Sx[9] = { See,             Seo,             See - c0e,
                    Soe,             Soo,             Soe - c0o,
                    See - r0e,       Seo - r0o,       See - r0e - c0e + x00 };
    const float cnt[9] = { 784.f, 784.f, 756.f,
                           784.f, 784.f, 756.f,
                           756.f, 756.f, 729.f };   // valid positions per tap
    #pragma unroll
    for (int k = 0; k < 9; ++k) tl[k][c] = a * Sx[k] + bb * cnt[k];
    __syncthreads();

    // thread = g*64 + o : output channel o, input-channel chunk g (64 ch)
    int o = threadIdx.x & 63;
    int g = threadIdx.x >> 6;
    float p = 0.f;
    for (int cc = g * 64; cc < g * 64 + 64; ++cc) {
        #pragma unroll
        for (int k = 0; k < 9; ++k)
            p += tl[k][cc] * conv_w[(k * C + cc) * CONV_OUT + o];  // (3,3,C,O)
    }
    part[g][o] = p;
    __syncthreads();

    if (threadIdx.x < CONV_OUT) {
        int o2 = threadIdx.x;
        float s = part[0][o2] + part[1][o2] + part[2][o2] + part[3][o2];
        cm[o2] = s * (1.f / 784.f) + conv_b[o2];   // mean of conv incl. bias
    }
    __syncthreads();

    if (threadIdx.x < ROUTES) {
        int r = threadIdx.x;
        float s = fc_b[r];
        for (int o2 = 0; o2 < CONV_OUT; ++o2) s += cm[o2] * fc_w[o2 * ROUTES + r];
        rxs[r] = s;
        out_routing[b * ROUTES + r] = s;
    }
    __syncthreads();

    if (threadIdx.x == 0) {
        int best = 0;                       // jnp.argmax: first max wins
        for (int r = 1; r < ROUTES; ++r) if (rxs[r] > rxs[best]) best = r;
        route[b] = best;
    }
}

// ---------------------------------------------------------------------------
// Kernel 3: gather 64 contiguous channels of the raw input per routed batch.
// One float4 per thread; coalesced read (L3-warm after k_reduce) and
// nontemporal coalesced write (output is never re-read -> don't evict the
// L3-resident input). Uses native ext_vector_type: HIP's float4 class is
// rejected by __builtin_nontemporal_store.
// ---------------------------------------------------------------------------
__global__ __launch_bounds__(256) void k_gather(const float* __restrict__ x,
                                                const int* __restrict__ route,
                                                float* __restrict__ out) {
    long idx = (long)blockIdx.x * blockDim.x + threadIdx.x;  // float4 id
    int j = (int)(idx & 15);                                 // 16 float4 / pixel
    long pixel = idx >> 4;
    int b = (int)(pixel / (H * W));
    const floatx4* xv = (const floatx4*)x;
    floatx4 v = xv[pixel * (C / 4) + (long)route[b] * (RW / 4) + j];
    __builtin_nontemporal_store(v, &((floatx4*)out)[idx]);
}

extern "C" void kernel_launch(void* const* d_in, const int* in_sizes, int n_in,
                              void* d_out, int out_size, void* d_ws, size_t ws_size,
                              hipStream_t stream) {
    const float* inputs = (const float*)d_in[0];
    const float* gamma  = (const float*)d_in[1];
    const float* beta   = (const float*)d_in[2];
    const float* mmean  = (const float*)d_in[3];
    const float* mvar   = (const float*)d_in[4];
    const float* conv_w = (const float*)d_in[5];
    const float* conv_b = (const float*)d_in[6];
    const float* fc_w   = (const float*)d_in[7];
    const float* fc_b   = (const float*)d_in[8];

    float* out   = (float*)d_out;
    float* ws    = (float*)d_ws;
    int*   route = (int*)((char*)d_ws + WS_FLOATS * sizeof(float));

    // All ws regions consumed downstream are fully written first -> no memset.
    k_reduce<<<B * H, 256, 0, stream>>>(inputs, ws);
    k_route<<<B, 256, 0, stream>>>(ws, gamma, beta, mmean, mvar,
                                   conv_w, conv_b, fc_w, fc_b,
                                   out + X_SIZE, route);
    long n4 = X_SIZE / 4;                    // 3,211,264 float4s
    k_gather<<<(int)(n4 / 256), 256, 0, stream>>>(inputs, route, out);
}

// Round 5
// 331.198 us; speedup vs baseline: 1.1436x; 1.0689x over previous
//
#include <hip/hip_runtime.h>

#define B 64
#define H 56
#define W 56
#define C 256
#define ROUTES 4
#define CONV_OUT 64
#define BN_EPS 0.001f
#define RW (C / ROUTES)            // 64 channels per route
#define X_SIZE ((long)B * H * W * RW)

// ws layout (floats):
//   P[B][9][C]      grid-sum primitives, atomically accumulated (zeroed by memset)
//   U[10][C][4]     folded (conv_w x fc_w x BN x counts) routing tensor
//   route[B] (int)
#define P_FLOATS ((long)B * 9 * C)          // 147,456
#define OFFU P_FLOATS
#define U_FLOATS (10L * C * 4)              // 10,240
#define OFFROUTE (OFFU + U_FLOATS)

typedef float floatx4 __attribute__((ext_vector_type(4)));

__device__ __forceinline__ void f4add(float4& a, const float4& v) {
    a.x += v.x; a.y += v.y; a.z += v.z; a.w += v.w;
}

// ---------------------------------------------------------------------------
// Kernel 1 (grid = B*H + 4):
//  blocks [0, B*H): per-row parity sums -> atomicAdd into P[b][j][c].
//    j: 0 See 1 Seo 2 Soe 3 Soo 4 c0e 5 c0o 6 r0e 7 r0o 8 x00
//  blocks [B*H, B*H+4): fold conv_w (read ONCE total) + fc_w + BN + tap counts
//    into U[10][C][4]:  routing[b][r] = sum_c( sum_j P[b][j][c]*U[j][c][r]
//                                              + U[9][c][r] ) + const[r]
// ---------------------------------------------------------------------------
__global__ __launch_bounds__(256) void k_reduce(const float* __restrict__ x,
                                                const float* __restrict__ gamma,
                                                const float* __restrict__ beta,
                                                const float* __restrict__ mmean,
                                                const float* __restrict__ mvar,
                                                const float* __restrict__ conv_w,
                                                const float* __restrict__ fc_w,
                                                float* __restrict__ ws) {
    int tid = threadIdx.x;

    if (blockIdx.x >= B * H) {
        // ---- fold branch: 4 blocks x 256 threads; thread = (c within 64, r)
        __shared__ float fcw_s[CONV_OUT * ROUTES];     // fc_w[o][r]
        fcw_s[tid] = fc_w[tid];                        // 256 == 64*4
        __syncthreads();

        int c = (blockIdx.x - B * H) * 64 + (tid >> 2);
        int r = tid & 3;

        float t[9];
        #pragma unroll
        for (int k = 0; k < 9; ++k) {
            const float4* w4 = (const float4*)conv_w + ((long)(k * C + c) * CONV_OUT) / 4;
            float s = 0.f;
            #pragma unroll
            for (int o4 = 0; o4 < 16; ++o4) {
                float4 wv = w4[o4];
                s += wv.x * fcw_s[(o4 * 4 + 0) * 4 + r];
                s += wv.y * fcw_s[(o4 * 4 + 1) * 4 + r];
                s += wv.z * fcw_s[(o4 * 4 + 2) * 4 + r];
                s += wv.w * fcw_s[(o4 * 4 + 3) * 4 + r];
            }
            t[k] = s;                                 // t[k] = sum_o w[k][c][o] fc_w[o][r]
        }

        float a  = gamma[c] * rsqrtf(mvar[c] + BN_EPS);
        float bb = beta[c] - mmean[c] * a;

        // Sx[k] in terms of P[j]:  Sx = {P0, P1, P0-P4, P2, P3, P2-P5,
        //                                P0-P6, P1-P7, P0-P6-P4+P8}
        float u[10];
        u[0] =  t[0] + t[2] + t[6] + t[8];
        u[1] =  t[1] + t[7];
        u[2] =  t[3] + t[5];
        u[3] =  t[4];
        u[4] = -(t[2] + t[8]);
        u[5] = -t[5];
        u[6] = -(t[6] + t[8]);
        u[7] = -t[7];
        u[8] =  t[8];
        // sum_k cnt[k]*t[k], cnt = {784,784,756,784,784,756,756,756,729}
        u[9] = 784.f * (t[0] + t[1] + t[3] + t[4])
             + 756.f * (t[2] + t[5] + t[6] + t[7])
             + 729.f * t[8];

        float* U = ws + OFFU;
        float sa = a * (1.f / 784.f);
        #pragma unroll
        for (int j = 0; j < 9; ++j) U[(j * C + c) * 4 + r] = sa * u[j];
        U[(9 * C + c) * 4 + r] = bb * (1.f / 784.f) * u[9];
        return;
    }

    // ---- row-reduce branch: one (b,h) row per block
    int blk = blockIdx.x;               // b*H + h
    int b = blk / H;
    int h = blk % H;
    int cg = tid & 63;
    int wg = tid >> 6;                  // 0..3 -> w = wg, wg+4, ...

    const float4* xv = (const float4*)x;
    long base = (long)blk * W * (C / 4) + cg;

    float4 v[14];
    #pragma unroll
    for (int i = 0; i < 14; ++i) v[i] = xv[base + (long)(wg + 4 * i) * (C / 4)];

    float4 a4 = {0,0,0,0}, b4 = {0,0,0,0};
    #pragma unroll
    for (int i = 0; i < 14; i += 2) { f4add(a4, v[i]); f4add(b4, v[i + 1]); }
    f4add(a4, b4);                      // sum over w === wg (mod 4)

    __shared__ float4 lds[4][64];
    lds[wg][cg] = a4;
    __syncthreads();

    float* Pb = ws + (long)b * 9 * C;
    int c0 = cg * 4;
    int hp = h & 1;
    #define ATOM4(j, q) { float* p = Pb + (j) * C + c0; \
        atomicAdd(p+0, (q).x); atomicAdd(p+1, (q).y); \
        atomicAdd(p+2, (q).z); atomicAdd(p+3, (q).w); }

    if (wg == 0) {                       // even-w sum (wg 0 & 2)
        float4 e = lds[0][cg]; f4add(e, lds[2][cg]);
        ATOM4(hp * 2, e);                // See / Soe
        ATOM4(4 + hp, v[0]);             // col-0 value
        if (h == 0) { ATOM4(6, e); ATOM4(8, v[0]); }   // r0e, x00
    } else if (wg == 1) {                // odd-w sum (wg 1 & 3)
        float4 o = lds[1][cg]; f4add(o, lds[3][cg]);
        ATOM4(hp * 2 + 1, o);            // Seo / Soo
        if (h == 0) ATOM4(7, o);         // r0o
    }
    #undef ATOM4
}

// ---------------------------------------------------------------------------
// Kernel 2: per-batch routing via the folded tensor. 64 blocks x 256 threads,
// 40 MACs/thread + block reduction + argmax.
// ---------------------------------------------------------------------------
__global__ __launch_bounds__(256) void k_route(const float* __restrict__ ws,
                                               const float* __restrict__ conv_b,
                                               const float* __restrict__ fc_w,
                                               const float* __restrict__ fc_b,
                                               float* __restrict__ out_routing,
                                               int* __restrict__ route) {
    __shared__ floatx4 red[256];
    __shared__ float rxs[ROUTES];

    int b = blockIdx.x;
    int c = threadIdx.x;
    const float* Pb = ws + (long)b * 9 * C;
    const floatx4* U4 = (const floatx4*)(ws + OFFU);

    floatx4 v = U4[9 * C + c];                    // bias-fold term
    #pragma unroll
    for (int j = 0; j < 9; ++j) v += Pb[j * C + c] * U4[j * C + c];

    red[c] = v;
    __syncthreads();
    #pragma unroll
    for (int s = 128; s >= 1; s >>= 1) {
        if (c < s) red[c] += red[c + s];
        __syncthreads();
    }

    if (c < ROUTES) {
        float cst = fc_b[c];
        for (int o = 0; o < CONV_OUT; ++o) cst += conv_b[o] * fc_w[o * ROUTES + c];
        float val = red[0][c] + cst;
        rxs[c] = val;
        out_routing[b * ROUTES + c] = val;
    }
    __syncthreads();
    if (c == 0) {
        int best = 0;                              // jnp.argmax: first max wins
        for (int r = 1; r < ROUTES; ++r) if (rxs[r] > rxs[best]) best = r;
        route[b] = best;
    }
}

// ---------------------------------------------------------------------------
// Kernel 3: gather. 3136 blocks x 256 threads x 4 independent float4 each
// (ILP for latency hiding); b is block-uniform (49 blocks per batch).
// Nontemporal store: output never re-read, keep input L3-resident.
// ---------------------------------------------------------------------------
__global__ __launch_bounds__(256) void k_gather(const float* __restrict__ x,
                                                const int* __restrict__ route,
                                                float* __restrict__ out) {
    long base4 = (long)blockIdx.x * 1024 + threadIdx.x;
    int b = blockIdx.x / 49;                       // 3136/64 pixels, 64 px/block
    int rt = route[b];
    const floatx4* xv = (const floatx4*)x;
    #pragma unroll
    for (int m = 0; m < 4; ++m) {
        long idx = base4 + m * 256;
        int j = (int)(idx & 15);                   // 16 float4 per pixel
        long pixel = idx >> 4;
        floatx4 v = xv[pixel * (C / 4) + (long)rt * (RW / 4) + j];
        __builtin_nontemporal_store(v, &((floatx4*)out)[idx]);
    }
}

extern "C" void kernel_launch(void* const* d_in, const int* in_sizes, int n_in,
                              void* d_out, int out_size, void* d_ws, size_t ws_size,
                              hipStream_t stream) {
    const float* inputs = (const float*)d_in[0];
    const float* gamma  = (const float*)d_in[1];
    const float* beta   = (const float*)d_in[2];
    const float* mmean  = (const float*)d_in[3];
    const float* mvar   = (const float*)d_in[4];
    const float* conv_w = (const float*)d_in[5];
    const float* conv_b = (const float*)d_in[6];
    const float* fc_w   = (const float*)d_in[7];
    const float* fc_b   = (const float*)d_in[8];

    float* out   = (float*)d_out;
    float* ws    = (float*)d_ws;
    int*   route = (int*)((char*)d_ws + OFFROUTE * sizeof(float));

    // Zero only P (atomic accumulators). U/route are fully overwritten.
    hipMemsetAsync(d_ws, 0, P_FLOATS * sizeof(float), stream);

    k_reduce<<<B * H + 4, 256, 0, stream>>>(inputs, gamma, beta, mmean, mvar,
                                            conv_w, fc_w, ws);
    k_route<<<B, 256, 0, stream>>>(ws, conv_b, fc_w, fc_b, out + X_SIZE, route);
    k_gather<<<3136, 256, 0, stream>>>(inputs, route, out);
}